// Round 8
// baseline (102.524 us; speedup 1.0000x reference)
//
#include <hip/hip_runtime.h>

// Problem constants
#define N_ 32
#define T_ 300
#define V_ 25
#define C_ 64      // C_IN
#define F_ 128
#define K_ 3
#define NT_ (N_ * T_)      // 9600 timesteps total
#define NBLK (NT_ / 4)     // 2400 blocks (4 waves/block, 1 timestep/wave)

typedef _Float16 f16;
typedef f16  f16x4v __attribute__((ext_vector_type(4)));
typedef f16  f16x8v __attribute__((ext_vector_type(8)));
typedef float f32x4v __attribute__((ext_vector_type(4)));

// workspace byte offsets
#define WS_WT 0         // f16 Wt[384][64]   = 49152 B
#define WS_A2 49152     // f16 A2[3][32][32] =  6144 B  (A2[k][w][v] = A[k][v][w], zero-padded)

// ---------------- prep: transpose/convert W, pad/convert A ----------------
__global__ void gcn_prep(const float* __restrict__ A, const float* __restrict__ W,
                         f16* __restrict__ Wt, f16* __restrict__ A2) {
    int tid = blockIdx.x * blockDim.x + threadIdx.x;
    if (tid < K_ * F_ * C_) {
        int d = tid >> 6, c = tid & 63;
        Wt[tid] = (f16)W[c * (K_ * F_) + d];
    }
    int t2 = tid - K_ * F_ * C_;
    if (t2 >= 0 && t2 < K_ * 32 * 32) {
        int k = t2 >> 10, r = t2 & 1023, w = r >> 5, v = r & 31;
        float val = (w < V_ && v < V_) ? A[(k * V_ + v) * V_ + w] : 0.0f;
        A2[t2] = (f16)val;
    }
}

// ---------------- barrier-free: one wave = one timestep ----------------
// per t, per k:
//   gemm1 (swapped): D1[v][d'] = sum_c x[t][v][c] * Wt[kF+d'][c]       (MFMA)
//   tbuf[f][v] = (f16)(D1[v][kF+f] + b[kF+f])   via ds_write_b64 (4 consecutive v/lane)
//   gemm2: accy[f][w] += sum_v tbuf[f][v] * A2[k][w][v]                (MFMA)
// store: y[n][t][w][f] <- accy, float4 (4 consecutive f/lane)
__global__ __launch_bounds__(256, 3) void gcn_fused(
    const float* __restrict__ x, const f16* __restrict__ Wt,
    const f16* __restrict__ A2g, const float* __restrict__ b,
    float* __restrict__ y)
{
    // per-wave transpose buffer: 128 rows (f) x 80 B (32 v f16 + 16 B slack)
    // stride 80: b128 reads stay 16B-aligned; bank spread ~2-way.
    __shared__ __align__(16) char tb_all[4][128 * 80];   // 40960 B total

    const int tid  = threadIdx.x;
    const int lane = tid & 63;
    const int wave = tid >> 6;
    const int l15  = lane & 15;
    const int lgr  = lane >> 4;       // 0..3
    const int koff = lgr * 8;

    char* tb = tb_all[wave];

    const int gid = blockIdx.x * 4 + wave;      // timestep id in [0, 9600)
    const int n = gid / T_, t = gid % T_;
    const float* xt = x + ((size_t)n * T_ + t) * (V_ * C_);

    // ---- x fragments (loaded once, reused for all 3 k) ----
    // A-frag of gemm1: lane row v = nt2*16 + l15, k-slice c = kt*32 + koff + j
    f16x8v xf[2][2];
    #pragma unroll
    for (int nt2 = 0; nt2 < 2; ++nt2) {
        const int v = nt2 * 16 + l15;
        const bool ok = (v < V_);
        #pragma unroll
        for (int kt = 0; kt < 2; ++kt) {
            float4 lo = {0.f, 0.f, 0.f, 0.f}, hi = {0.f, 0.f, 0.f, 0.f};
            if (ok) {
                const float4* p = (const float4*)(xt + v * C_ + kt * 32 + koff);
                lo = p[0]; hi = p[1];
            }
            f16x8v f;
            f[0] = (f16)lo.x; f[1] = (f16)lo.y; f[2] = (f16)lo.z; f[3] = (f16)lo.w;
            f[4] = (f16)hi.x; f[5] = (f16)hi.y; f[6] = (f16)hi.z; f[7] = (f16)hi.w;
            xf[nt2][kt] = f;
        }
    }

    f32x4v zero4 = {0.f, 0.f, 0.f, 0.f};
    f32x4v accy[8][2];                 // [f-tile][w-tile], accumulated over k
    #pragma unroll
    for (int ft = 0; ft < 8; ++ft)
        #pragma unroll
        for (int nt = 0; nt < 2; ++nt)
            accy[ft][nt] = zero4;

    #pragma unroll 1                   // keep k dynamic: stop wfr hoisting across k
    for (int k = 0; k < K_; ++k) {
        // B-frags of gemm2: lane row w = nt*16 + l15, k-slice v = koff + j
        f16x8v a2f[2];
        #pragma unroll
        for (int nt = 0; nt < 2; ++nt)
            a2f[nt] = *(const f16x8v*)(A2g + (size_t)k * 1024 + (nt * 16 + l15) * 32 + koff);

        // ---- gemm1, two d-halves of 64 ----
        #pragma unroll
        for (int half = 0; half < 2; ++half) {
            f16x8v wfr[4][2];
            #pragma unroll
            for (int mt = 0; mt < 4; ++mt) {
                const int d = k * F_ + (half * 4 + mt) * 16 + l15;
                #pragma unroll
                for (int kt = 0; kt < 2; ++kt)
                    wfr[mt][kt] = *(const f16x8v*)(Wt + (size_t)d * C_ + kt * 32 + koff);
            }
            f32x4v acc1[4][2];
            #pragma unroll
            for (int mt = 0; mt < 4; ++mt)
                #pragma unroll
                for (int nt2 = 0; nt2 < 2; ++nt2)
                    acc1[mt][nt2] = zero4;
            #pragma unroll
            for (int kt = 0; kt < 2; ++kt)
                #pragma unroll
                for (int mt = 0; mt < 4; ++mt)
                    #pragma unroll
                    for (int nt2 = 0; nt2 < 2; ++nt2)
                        acc1[mt][nt2] = __builtin_amdgcn_mfma_f32_16x16x32_f16(
                            xf[nt2][kt], wfr[mt][kt], acc1[mt][nt2], 0, 0, 0);
            // write h + bias: lane holds D1[v = nt2*16+lgr*4+r][f-col = (half*4+mt)*16+l15]
            #pragma unroll
            for (int mt = 0; mt < 4; ++mt) {
                const int f = (half * 4 + mt) * 16 + l15;
                const float bv = b[k * F_ + f];
                #pragma unroll
                for (int nt2 = 0; nt2 < 2; ++nt2) {
                    f16x4v h4;
                    #pragma unroll
                    for (int r = 0; r < 4; ++r) h4[r] = (f16)(acc1[mt][nt2][r] + bv);
                    *(f16x4v*)(tb + f * 80 + nt2 * 32 + lgr * 8) = h4;
                }
            }
        }

        // ---- gemm2: accy[f][w] += tbuf[f][:] x A2t[w][:] ----
        #pragma unroll
        for (int ft = 0; ft < 8; ++ft) {
            const f16x8v afr = *(const f16x8v*)(tb + (ft * 16 + l15) * 80 + lgr * 16);
            #pragma unroll
            for (int nt = 0; nt < 2; ++nt)
                accy[ft][nt] = __builtin_amdgcn_mfma_f32_16x16x32_f16(
                    afr, a2f[nt], accy[ft][nt], 0, 0, 0);
        }
    }

    // ---- store: lane holds accy[ft][nt] = y[w = nt*16+l15][f = ft*16 + lgr*4 + r], r=0..3 ----
    {
        float* yt = y + (((size_t)n * T_ + t) * V_) * F_;
        #pragma unroll
        for (int nt = 0; nt < 2; ++nt) {
            const int w = nt * 16 + l15;
            if (w < V_) {
                #pragma unroll
                for (int ft = 0; ft < 8; ++ft) {
                    float4 o;
                    o.x = accy[ft][nt][0]; o.y = accy[ft][nt][1];
                    o.z = accy[ft][nt][2]; o.w = accy[ft][nt][3];
                    *(float4*)(yt + (size_t)w * F_ + ft * 16 + lgr * 4) = o;
                }
            }
        }
    }
}

extern "C" void kernel_launch(void* const* d_in, const int* in_sizes, int n_in,
                              void* d_out, int out_size, void* d_ws, size_t ws_size,
                              hipStream_t stream) {
    const float* x = (const float*)d_in[0];
    const float* A = (const float*)d_in[1];
    const float* W = (const float*)d_in[2];
    const float* b = (const float*)d_in[3];
    float* yout = (float*)d_out;

    f16* Wt = (f16*)((char*)d_ws + WS_WT);
    f16* A2 = (f16*)((char*)d_ws + WS_A2);

    const int prep_threads = K_ * F_ * C_ + K_ * 32 * 32;  // 27648
    gcn_prep<<<(prep_threads + 255) / 256, 256, 0, stream>>>(A, W, Wt, A2);
    gcn_fused<<<NBLK, 256, 0, stream>>>(x, Wt, A2, b, yout);
}

// Round 10
// 92.232 us; speedup vs baseline: 1.1116x; 1.1116x over previous
//
#include <hip/hip_runtime.h>

// Problem constants
#define N_ 32
#define T_ 300
#define V_ 25
#define C_ 64      // C_IN
#define F_ 128
#define K_ 3
#define NBLK (N_ * T_ / 2)   // 4800 blocks: block = 4 waves = 2 timesteps x 2 f-halves

typedef _Float16 f16;
typedef f16  f16x4v __attribute__((ext_vector_type(4)));
typedef f16  f16x8v __attribute__((ext_vector_type(8)));
typedef float f32x4v __attribute__((ext_vector_type(4)));

// workspace byte offsets
#define WS_WT  0        // f16 Wt[384][64]          = 49152 B
#define WS_A2F 49152    // f16 a2frag[3][2][2][64][4] = 6144 B (exact gemm2 B-frag order)

// ---------------- prep: transpose/convert W; A -> B-fragment layout ----------------
// a2frag[(((k*2+s)*2+wt)*64+lane)*4+e] = A[k][v][w], v = s*16+(lane>>4)*4+e, w = wt*16+(lane&15)
// (zero-padded: v>=25 rows MUST be zero — they multiply bias-contaminated h lanes)
__global__ void gcn_prep(const float* __restrict__ A, const float* __restrict__ W,
                         f16* __restrict__ Wt, f16* __restrict__ A2F) {
    int tid = blockIdx.x * blockDim.x + threadIdx.x;
    if (tid < K_ * F_ * C_) {
        int d = tid >> 6, c = tid & 63;
        Wt[tid] = (f16)W[c * (K_ * F_) + d];
    }
    int t2 = tid - K_ * F_ * C_;
    if (t2 >= 0 && t2 < K_ * 2 * 2 * 64 * 4) {
        int e = t2 & 3, lane = (t2 >> 2) & 63, wt = (t2 >> 8) & 1, s = (t2 >> 9) & 1, k = t2 >> 10;
        int v = s * 16 + (lane >> 4) * 4 + e;
        int w = wt * 16 + (lane & 15);
        A2F[t2] = (v < V_ && w < V_) ? (f16)A[(k * V_ + v) * V_ + w] : (f16)0.f;
    }
}

// ---------------- fused, zero-LDS, zero-barrier: wave = (timestep, f-half) ----------------
// gemm1 (16x16x32): D1[v][f'] = sum_c x[t][v][c] * Wt[kF+f'][c]   (lane: f'=l15, v=lgr*4+r)
// bias+cvt in registers: h4 = (f16)(D1 + b)  == A-frag of 16x16x16 (m=f'=l15, k=v=lgr*4+e)
// gemm2 (16x16x16, v-steps of 16): accy[f'][w] += h4 x A2frag      (lane: w=l15, f'=lgr*4+r)
__global__ __launch_bounds__(256, 4) void gcn_fused(
    const float* __restrict__ x, const f16* __restrict__ Wt,
    const f16* __restrict__ A2F, const float* __restrict__ b,
    float* __restrict__ y)
{
    const int tid  = threadIdx.x;
    const int lane = tid & 63;
    const int wave = tid >> 6;
    const int l15  = lane & 15;
    const int lgr  = lane >> 4;       // 0..3

    const int tloc = wave >> 1;       // 0..1: timestep within block
    const int fh   = wave & 1;        // f-half (0: f 0..63, 1: f 64..127)
    const int gid  = blockIdx.x * 2 + tloc;   // global timestep = n*T + t
    const float* xt = x + (size_t)gid * (V_ * C_);

    // ---- x A-fragments (loaded once, reused all k): m=v=vt*16+l15, k-slice c=kt*32+lgr*8+e ----
    f16x8v xf[2][2];
    #pragma unroll
    for (int vt = 0; vt < 2; ++vt) {
        const int v = vt * 16 + l15;
        const bool ok = (v < V_);
        #pragma unroll
        for (int kt = 0; kt < 2; ++kt) {
            float4 lo = {0.f, 0.f, 0.f, 0.f}, hi = {0.f, 0.f, 0.f, 0.f};
            if (ok) {
                const float4* p = (const float4*)(xt + v * C_ + kt * 32 + lgr * 8);
                lo = p[0]; hi = p[1];
            }
            f16x8v f;
            f[0] = (f16)lo.x; f[1] = (f16)lo.y; f[2] = (f16)lo.z; f[3] = (f16)lo.w;
            f[4] = (f16)hi.x; f[5] = (f16)hi.y; f[6] = (f16)hi.z; f[7] = (f16)hi.w;
            xf[vt][kt] = f;
        }
    }

    f32x4v zero4 = {0.f, 0.f, 0.f, 0.f};
    f32x4v accy[4][2];                 // [ft][wt]; accumulated over k and v-steps
    #pragma unroll
    for (int ft = 0; ft < 4; ++ft)
        #pragma unroll
        for (int wt = 0; wt < 2; ++wt)
            accy[ft][wt] = zero4;

    #pragma unroll 1                   // keep k dynamic: no cross-k operand hoisting
    for (int k = 0; k < K_; ++k) {
        // gemm2 B-frags (prepped exact layout): [s][wt], 8B per lane, L2-hot
        f16x4v a2w[2][2];
        #pragma unroll
        for (int s = 0; s < 2; ++s)
            #pragma unroll
            for (int wt = 0; wt < 2; ++wt)
                a2w[s][wt] = *(const f16x4v*)(A2F + (((size_t)(k * 2 + s) * 2 + wt) * 64 + lane) * 4);

        #pragma unroll
        for (int ft = 0; ft < 4; ++ft) {
            const int f = fh * 64 + ft * 16 + l15;
            // gemm1 B-frag: row d=k*128+f, c-slice kt*32+lgr*8 (contiguous 16B)
            f16x8v wfr[2];
            #pragma unroll
            for (int kt = 0; kt < 2; ++kt)
                wfr[kt] = *(const f16x8v*)(Wt + (size_t)(k * F_ + f) * C_ + kt * 32 + lgr * 8);

            f32x4v acc1[2] = {zero4, zero4};   // [vt]: D1 rows v = vt*16+lgr*4+r, col f
            #pragma unroll
            for (int kt = 0; kt < 2; ++kt)
                #pragma unroll
                for (int vt = 0; vt < 2; ++vt)
                    acc1[vt] = __builtin_amdgcn_mfma_f32_16x16x32_f16(
                        xf[vt][kt], wfr[kt], acc1[vt], 0, 0, 0);

            const float bv = b[k * F_ + f];
            // bias + f16 cvt -> gemm2 A-frag (m=f=l15, k=v=lgr*4+e); v-step s = vt
            #pragma unroll
            for (int s = 0; s < 2; ++s) {
                f16x4v h4;
                #pragma unroll
                for (int e = 0; e < 4; ++e) h4[e] = (f16)(acc1[s][e] + bv);
                #pragma unroll
                for (int wt = 0; wt < 2; ++wt)
                    accy[ft][wt] = __builtin_amdgcn_mfma_f32_16x16x16f16(
                        h4, a2w[s][wt], accy[ft][wt], 0, 0, 0);
            }
        }
    }

    // ---- store: lane holds accy[ft][wt] = y[w = wt*16+l15][f = fh*64+ft*16+lgr*4+r] ----
    {
        float* yt = y + (size_t)gid * (V_ * F_);
        #pragma unroll
        for (int wt = 0; wt < 2; ++wt) {
            const int w = wt * 16 + l15;
            if (w < V_) {
                #pragma unroll
                for (int ft = 0; ft < 4; ++ft) {
                    float4 o;
                    o.x = accy[ft][wt][0]; o.y = accy[ft][wt][1];
                    o.z = accy[ft][wt][2]; o.w = accy[ft][wt][3];
                    *(float4*)(yt + (size_t)w * F_ + fh * 64 + ft * 16 + lgr * 4) = o;
                }
            }
        }
    }
}

extern "C" void kernel_launch(void* const* d_in, const int* in_sizes, int n_in,
                              void* d_out, int out_size, void* d_ws, size_t ws_size,
                              hipStream_t stream) {
    const float* x = (const float*)d_in[0];
    const float* A = (const float*)d_in[1];
    const float* W = (const float*)d_in[2];
    const float* b = (const float*)d_in[3];
    float* yout = (float*)d_out;

    f16* Wt  = (f16*)((char*)d_ws + WS_WT);
    f16* A2F = (f16*)((char*)d_ws + WS_A2F);

    const int prep_threads = K_ * F_ * C_ + K_ * 2 * 2 * 64 * 4;  // 27648
    gcn_prep<<<(prep_threads + 255) / 256, 256, 0, stream>>>(A, W, Wt, A2F);
    gcn_fused<<<NBLK, 256, 0, stream>>>(x, Wt, A2F, b, yout);
}